// Round 1
// 367.275 us; speedup vs baseline: 1.0014x; 1.0014x over previous
//
#include <hip/hip_runtime.h>
#include <hip/hip_bf16.h>

// bf16x8 fragment (4 VGPRs) for gfx950 mfma_f32_16x16x32_bf16.
typedef short bf16x8 __attribute__((ext_vector_type(8)));
typedef float floatx4 __attribute__((ext_vector_type(4)));

union U128 { bf16x8 h; __hip_bfloat16 e[8]; };

__device__ __forceinline__ bf16x8 cvt8(const float4& a, const float4& b) {
  U128 u;
  u.e[0] = __float2bfloat16(a.x); u.e[1] = __float2bfloat16(a.y);
  u.e[2] = __float2bfloat16(a.z); u.e[3] = __float2bfloat16(a.w);
  u.e[4] = __float2bfloat16(b.x); u.e[5] = __float2bfloat16(b.y);
  u.e[6] = __float2bfloat16(b.z); u.e[7] = __float2bfloat16(b.w);
  return u.h;
}

// Inputs fp32 AND output fp32 (reference dtypes).
// One pixel (h,w) = 64 z-rows x 16 ch per wave-iteration.
// A = [dv(16) | z_embed(16)] -> K=32; B = w1 (32x64); C = b1 broadcast.
// A-frag layout: A[m=lane&15][k=(lane>>4)*8+j]; byte offset within pixel:
//   1024*t + 64*m + 32*(q&1)   (same form for dv (q<2) and z_embed (q>=2)).
// Design is invariant to any self-consistent MFMA layout permutation:
// k-perm cancels A<->B, col-perm cancels B/C/D, row mapping irrelevant
// because relu + z-sum covers all rows.
//
// R1 change vs previous best: single fp32 load buffer (L[8]) instead of
// curA/nxtA double-buffer; z_embed fragments live PERMANENTLY in af[] for
// q>=2 lanes (their role never changes), so no per-iteration select and no
// separate aez storage. VGPR ~150 -> ~100 => 4 waves/SIMD via
// __launch_bounds__(256,4). Pipeline: cvt(L)->af at loop head (prev-iter
// loads have had a full MFMA block to land), then reissue loads into L.
__global__ __launch_bounds__(256, 4) void bev_kernel(
    const float* __restrict__ dv,   // [P][64][16]
    const float* __restrict__ ze,   // [64][16]
    const float* __restrict__ w1,   // [32][64]
    const float* __restrict__ b1,   // [64]
    const float* __restrict__ gam,  // [64]
    const float* __restrict__ bet,  // [64]
    float* __restrict__ out,        // [P][64] fp32
    int P)
{
  const int lane = threadIdx.x & 63;
  const int wid  = blockIdx.x * (blockDim.x >> 6) + (threadIdx.x >> 6);
  const int nw   = gridDim.x * (blockDim.x >> 6);
  const int q = lane >> 4;   // quad: 0,1 -> dv k-halves; 2,3 -> z_embed k-halves
  const int m = lane & 15;   // A row within tile / output column within N-block

  // B fragments: B[k=q*8+j][n=nb*16+m], w1 row-major [32][64], fp32 -> bf16.
  bf16x8 bfrag[4];
  #pragma unroll
  for (int nb = 0; nb < 4; ++nb) {
    U128 t;
    #pragma unroll
    for (int j = 0; j < 8; ++j)
      t.e[j] = __float2bfloat16(w1[(q * 8 + j) * 64 + nb * 16 + m]);
    bfrag[nb] = t.h;
  }
  // C init = b1[n] broadcast (bias added before relu, as in ref).
  floatx4 cinit[4];
  #pragma unroll
  for (int nb = 0; nb < 4; ++nb) {
    float b = b1[nb * 16 + m];
    cinit[nb] = (floatx4){b, b, b, b};
  }
  const float gl = gam[lane];
  const float bl = bet[lane];

  // A fragments. q>=2 lanes: permanently z_embed (pixel-invariant, set once,
  // never overwritten). In-bounds for ALL lanes (max byte offset
  // 1024*3+64*15+32+16+16 = 4096 <= 4096); q<2 lanes overwrite per pixel.
  bf16x8 af[4];
  #pragma unroll
  for (int t = 0; t < 4; ++t) {
    const char* zp = (const char*)ze + 1024 * t + 64 * m + 32 * (q & 1);
    af[t] = cvt8(*(const float4*)zp, *(const float4*)(zp + 16));
  }

  const char* p = (const char*)dv + (long)wid * 4096 + 64 * m + 32 * (q & 1);
  const long step = (long)nw * 4096;

  float4 L[8];
  if (wid < P && q < 2) {
    #pragma unroll
    for (int t = 0; t < 4; ++t) {
      L[2 * t]     = *(const float4*)(p + 1024 * t);
      L[2 * t + 1] = *(const float4*)(p + 1024 * t + 16);
    }
  }
  for (int pix = wid; pix < P; pix += nw) {
    // Convert the loads issued last iteration (or prologue) into A-frags.
    if (q < 2) {
      #pragma unroll
      for (int t = 0; t < 4; ++t)
        af[t] = cvt8(L[2 * t], L[2 * t + 1]);
    }
    // Reissue loads into the same L buffer for the next pixel (WAR on L is
    // respected: loads issue after cvt consumed the registers).
    p += step;
    if (q < 2 && pix + nw < P) {
      #pragma unroll
      for (int t = 0; t < 4; ++t) {
        L[2 * t]     = *(const float4*)(p + 1024 * t);
        L[2 * t + 1] = *(const float4*)(p + 1024 * t + 16);
      }
    }

    float acc[4] = {0.f, 0.f, 0.f, 0.f};  // per-lane z-partials, one per N-block
    #pragma unroll
    for (int t = 0; t < 4; ++t) {
      #pragma unroll
      for (int nb = 0; nb < 4; ++nb) {
        floatx4 d = __builtin_amdgcn_mfma_f32_16x16x32_bf16(af[t], bfrag[nb], cinit[nb], 0, 0, 0);
        // This lane holds 4 D rows (z values) of col n = nb*16+m. relu+z-sum;
        // exact row ids irrelevant (full coverage, summed).
        acc[nb] += (fmaxf(d[0], 0.f) + fmaxf(d[1], 0.f)) +
                   (fmaxf(d[2], 0.f) + fmaxf(d[3], 0.f));
      }
    }
    // finish z-sum across quads (lanes m, m+16, m+32, m+48 share col n)
    #pragma unroll
    for (int nb = 0; nb < 4; ++nb) {
      acc[nb] += __shfl_xor(acc[nb], 16, 64);
      acc[nb] += __shfl_xor(acc[nb], 32, 64);
    }
    // LayerNorm over d=64: lane holds d = nb*16+m (identical across quads).
    float s  = acc[0] + acc[1] + acc[2] + acc[3];
    float sq = acc[0]*acc[0] + acc[1]*acc[1] + acc[2]*acc[2] + acc[3]*acc[3];
    #pragma unroll
    for (int off = 1; off <= 8; off <<= 1) {
      s  += __shfl_xor(s, off, 64);
      sq += __shfl_xor(sq, off, 64);
    }
    const float mean = s * 0.015625f;
    const float var  = sq * 0.015625f - mean * mean;
    const float rs   = rsqrtf(var + 1e-5f);
    const float v = (q == 0) ? acc[0] : (q == 1) ? acc[1] : (q == 2) ? acc[2] : acc[3];
    out[(long)pix * 64 + lane] = (v - mean) * rs * gl + bl;   // fp32 store
  }
}

extern "C" void kernel_launch(void* const* d_in, const int* in_sizes, int n_in,
                              void* d_out, int out_size, void* d_ws, size_t ws_size,
                              hipStream_t stream) {
  const float* dv  = (const float*)d_in[0];
  const float* ze  = (const float*)d_in[1];
  const float* w1  = (const float*)d_in[2];
  const float* b1  = (const float*)d_in[3];
  const float* gam = (const float*)d_in[4];
  const float* bet = (const float*)d_in[5];
  float* out = (float*)d_out;

  const int P = in_sizes[0] / (64 * 16);  // H*W pixels (B=1)
  dim3 grid(2048), block(256);            // 8192 waves -> 8 pixels/wave at P=65536
  bev_kernel<<<grid, block, 0, stream>>>(dv, ze, w1, b1, gam, bet, out, P);
}